// Round 8
// baseline (796.996 us; speedup 1.0000x reference)
//
#include <hip/hip_runtime.h>

typedef __bf16 bf16_t;
typedef __bf16 bf16x4 __attribute__((ext_vector_type(4)));
typedef __bf16 bf16x8 __attribute__((ext_vector_type(8)));
typedef float f32x4 __attribute__((ext_vector_type(4)));

// async global->LDS, 16B per lane, wave-uniform LDS base + lane*16
__device__ inline void gl_lds16(const bf16_t* g, bf16_t* l) {
  __builtin_amdgcn_global_load_lds(
      (const __attribute__((address_space(1))) void*)g,
      (__attribute__((address_space(3))) void*)l, 16, 0, 0);
}

// ---------------- halo-ring zero helper --------------------------------------
struct BZJob { bf16_t* p; int Wp, Hp, nsA, ringN, count; };  // count = 8*ringN*32

__device__ inline void ring_zero_body(const BZJob& J, int idx) {
  if (idx >= J.count) return;
  const int c8 = idx & 31;
  const int rp = idx >> 5;
  const int n = rp / J.ringN;
  const int r = rp - n * J.ringN;
  int y, x;
  if (r < J.Wp)          { y = 0;         x = r; }
  else if (r < 2 * J.Wp) { y = J.Hp - 1;  x = r - J.Wp; }
  else {
    const int rr = r - 2 * J.Wp;
    y = 1 + (rr >> 1);
    x = (rr & 1) ? (J.Wp - 1) : 0;
  }
  bf16x8 z;
#pragma unroll
  for (int k = 0; k < 8; ++k) z[k] = (bf16_t)0.0f;
  *(bf16x8*)&J.p[((size_t)n * J.nsA + y * J.Wp + x) * 256 + c8 * 8] = z;
}

// ---------------- NCHW->NHWC transpose body ----------------------------------
__device__ inline void transpose_body(const float* __restrict__ in,
                                      bf16_t* __restrict__ out, int C, int HW,
                                      int n, int c0, int p0, float (*tile)[65]) {
  const int t = threadIdx.x;
  const float* src = in + ((size_t)n * C + c0) * HW + p0;
  const int cl = t >> 6;
  const int pl = t & 63;
#pragma unroll
  for (int i = 0; i < 16; ++i)
    tile[cl + i * 4][pl] = src[(size_t)(cl + i * 4) * HW + pl];
  __syncthreads();
  bf16_t* dst = out + ((size_t)n * HW + p0) * C + c0;
  const int g = t & 7;
  const int pbase = t >> 3;
#pragma unroll
  for (int pass = 0; pass < 2; ++pass) {
    const int px = pbase + pass * 32;
    bf16x8 v;
#pragma unroll
    for (int j = 0; j < 8; ++j) v[j] = (bf16_t)tile[g * 8 + j][px];
    *(bf16x8*)&dst[(size_t)px * C + g * 8] = v;
  }
}

// ---------------- mega-prep: weights + anchors + transposes + rings ----------
// blocks [0,896): LWT copy-cast (float4 -> bf16x4).
// [896,3200): W33 transpose, coalesced (1 block per (sgi,o)).
// [3200,3263): anchors.
// [3263,7359): transpose feat3. [7359,9407): feat4. [9407,10431): feat5.
// [10431,11351): halo rings of Lp*/Pp*.
struct WSrc {
  const float *lw0, *lw1, *lw2;
  const float* w9[9];   // fw0,fw1,fw2,cw0,cw1,cw2,rw0,rw1,rw2
  int O9[9];            // 256,256,256,256,256,240,256,256,12
};
struct PrepArgs {
  WSrc s;
  const float *feat3, *feat4, *feat5;
  bf16_t *XS3, *XS4, *XS5;
  bf16_t *LWT0, *LWT1, *LWT2, *W33;
  float* anchors_out;
  BZJob rz[6];
};
__global__ __launch_bounds__(256)
void mega_prep(PrepArgs P) {
  __shared__ float tile[64][65];
  const int bid = blockIdx.x;
  if (bid < 896) {
    const int idx = (bid * 256 + threadIdx.x) * 4;
    const float* src;
    bf16_t* dst;
    int off;
    if (idx < 131072)      { src = P.s.lw0; dst = P.LWT0; off = idx; }
    else if (idx < 393216) { src = P.s.lw1; dst = P.LWT1; off = idx - 131072; }
    else                   { src = P.s.lw2; dst = P.LWT2; off = idx - 393216; }
    const f32x4 v = *(const f32x4*)&src[off];
    bf16x4 o4;
#pragma unroll
    for (int k = 0; k < 4; ++k) o4[k] = (bf16_t)v[k];
    *(bf16x4*)&dst[off] = o4;
    return;
  }
  if (bid < 3200) {
    const int r = bid - 896;           // sgi*256 + o
    const int sgi = r >> 8, o = r & 255;
    const int ci = threadIdx.x;
    const float* src = P.s.w9[sgi];
    const int O = P.s.O9[sgi];
    float v[9];
    if (o < O) {
      const float* p = &src[((size_t)o * 256 + ci) * 9];
#pragma unroll
      for (int k = 0; k < 9; ++k) v[k] = p[k];
    } else {
#pragma unroll
      for (int k = 0; k < 9; ++k) v[k] = 0.0f;
    }
    bf16_t* dst = P.W33 + (size_t)sgi * 589824 + o * 256 + ci;
#pragma unroll
    for (int k = 0; k < 9; ++k) dst[(size_t)k * 65536] = (bf16_t)v[k];
    return;
  }
  if (bid < 3263) {
    int rr = (bid - 3200) * 256 + threadIdx.x;
    if (rr >= 16128) return;
    int local, w, stride;
    float bs;
    if (rr < 12288)      { local = rr;          w = 64; stride = 8;  bs = 32.f;  }
    else if (rr < 15360) { local = rr - 12288;  w = 32; stride = 16; bs = 64.f;  }
    else                 { local = rr - 15360;  w = 16; stride = 32; bs = 128.f; }
    const int a = local % 3;
    const int sxy = local / 3;
    const int y = sxy / w, x = sxy - y * w;
    const float ar = (a == 0) ? 0.5f : (a == 1) ? 1.0f : 2.0f;
    const float sq = sqrtf(ar);
    const float hw_ = bs * sq * 0.5f, hh = bs / sq * 0.5f;
    const float cx = (float)x * (float)stride, cy = (float)y * (float)stride;
    P.anchors_out[(size_t)rr * 4 + 0] = cx - hw_;
    P.anchors_out[(size_t)rr * 4 + 1] = cy - hh;
    P.anchors_out[(size_t)rr * 4 + 2] = cx + hw_;
    P.anchors_out[(size_t)rr * 4 + 3] = cy + hh;
    return;
  }
  if (bid < 7359) {   // feat3: C=512, HW=4096, grid 64x8x8
    const int q = bid - 3263;
    transpose_body(P.feat3, P.XS3, 512, 4096, q >> 9, ((q >> 6) & 7) * 64,
                   (q & 63) * 64, tile);
    return;
  }
  if (bid < 9407) {   // feat4: C=1024, HW=1024, grid 16x16x8
    const int q = bid - 7359;
    transpose_body(P.feat4, P.XS4, 1024, 1024, q >> 8, ((q >> 4) & 15) * 64,
                   (q & 15) * 64, tile);
    return;
  }
  if (bid < 10431) {  // feat5: C=2048, HW=256, grid 4x32x8
    const int q = bid - 9407;
    transpose_body(P.feat5, P.XS5, 2048, 256, q >> 7, ((q >> 2) & 31) * 64,
                   (q & 3) * 64, tile);
    return;
  }
  // rings of Lp*/Pp*
  int idx = (bid - 10431) * 256 + threadIdx.x;
  int ji = 0;
#pragma unroll 1
  for (; ji < 5; ++ji) {
    if (idx < P.rz[ji].count) break;
    idx -= P.rz[ji].count;
  }
  ring_zero_body(P.rz[ji], idx);
}

// ---------------- post-conv1: TA rings + fused top-down up2 ------------------
// [0,1052): rings (6 TA jobs + Lp1n ring).
// [1052,2076): Lp1n = Lp1 + up2(Lp2)            (262144 elems of 8 ch)
// [2076,6172): Lp0 += up2(Lp1_old) + up4(Lp2)   (1048576 elems of 8 ch)
//   == Lp0 += up2(Lp1_new), since up2(Lp1new)[y,x] = Lp1[y>>1] + Lp2[y>>2].
struct Post1 {
  BZJob rz[7];
  bf16_t *Lp0, *Lp1, *Lp2, *Lp1n;
};
__global__ __launch_bounds__(256)
void post1_k(Post1 P) {
  const int bid = blockIdx.x;
  if (bid < 1052) {
    int idx = bid * 256 + threadIdx.x;
    int ji = 0;
#pragma unroll 1
    for (; ji < 6; ++ji) {
      if (idx < P.rz[ji].count) break;
      idx -= P.rz[ji].count;
    }
    ring_zero_body(P.rz[ji], idx);
    return;
  }
  if (bid < 2076) {
    const int idx = (bid - 1052) * 256 + threadIdx.x;   // < 262144
    const int c8 = idx & 31;
    const int pos = idx >> 5;
    const int n = pos >> 10;
    const int rem = pos & 1023;
    const int y = rem >> 5, x = rem & 31;
    const bf16_t* s1 = P.Lp1 + ((size_t)n * 1156 + (y + 1) * 34 + (x + 1)) * 256 + c8 * 8;
    const bf16_t* s2 = P.Lp2 + ((size_t)n * 324 + ((y >> 1) + 1) * 18 + ((x >> 1) + 1)) * 256 + c8 * 8;
    bf16_t* d = P.Lp1n + ((size_t)n * 1156 + (y + 1) * 34 + (x + 1)) * 256 + c8 * 8;
    bf16x8 a = *(const bf16x8*)s1;
    bf16x8 b = *(const bf16x8*)s2;
    bf16x8 o;
#pragma unroll
    for (int k = 0; k < 8; ++k) o[k] = (bf16_t)((float)a[k] + (float)b[k]);
    *(bf16x8*)d = o;
    return;
  }
  const int idx = (bid - 2076) * 256 + threadIdx.x;     // < 1048576
  const int c8 = idx & 31;
  const int pos = idx >> 5;
  const int n = pos >> 12;
  const int rem = pos & 4095;
  const int y = rem >> 6, x = rem & 63;
  bf16_t* d = P.Lp0 + ((size_t)n * 4356 + (y + 1) * 66 + (x + 1)) * 256 + c8 * 8;
  const bf16_t* s1 = P.Lp1 + ((size_t)n * 1156 + ((y >> 1) + 1) * 34 + ((x >> 1) + 1)) * 256 + c8 * 8;
  const bf16_t* s2 = P.Lp2 + ((size_t)n * 324 + ((y >> 2) + 1) * 18 + ((x >> 2) + 1)) * 256 + c8 * 8;
  bf16x8 dv = *(bf16x8*)d;
  bf16x8 a = *(const bf16x8*)s1;
  bf16x8 b = *(const bf16x8*)s2;
#pragma unroll
  for (int k = 0; k < 8; ++k)
    dv[k] = (bf16_t)((float)dv[k] + (float)a[k] + (float)b[k]);
  *(bf16x8*)d = dv;
}

// ---------------- 1x1 conv (laterals), bf16 MFMA (round-0 proven form) -------
struct Job1 {
  const bf16_t* A;    // unpadded NHWC
  const bf16_t* Wt;   // [256][Cin]
  const float* bias;
  bf16_t* outb;       // padded NHWC out
  int mtiles, lw, lhw, oWp, onstride, Cin, pad0, pad1;
};
struct Job1Pack { Job1 j[3]; };

__global__ __launch_bounds__(256, 2)
void conv1_batch(Job1Pack jp) {
  __shared__ __align__(16) bf16_t As[128 * 32];
  __shared__ __align__(16) bf16_t Bs[128 * 32];
  // XCD-aware chunked swizzle (grid % 8 == 0)
  const int cpx = gridDim.x >> 3;
  int b = (blockIdx.x & 7) * cpx + (blockIdx.x >> 3);
  int ji = 0;
#pragma unroll 1
  for (; ji < 2; ++ji) {
    int sz = jp.j[ji].mtiles * 2;
    if (b < sz) break;
    b -= sz;
  }
  const Job1 J = jp.j[ji];
  const int nt = b & 1, mt = b >> 1;
  const int m0 = mt * 128, n0 = nt * 128;
  const int t = threadIdx.x, l = t & 63, w = t >> 6;
  const int W = 1 << J.lw, HW = 1 << J.lhw;
  const int sr = l >> 2, seg = (l & 3) * 8;
  const bf16_t* aptr[2];
  const bf16_t* bptr[2];
  bf16_t* alds[2];
  bf16_t* blds[2];
#pragma unroll
  for (int q = 0; q < 2; ++q) {
    const int r = w * 32 + q * 16 + sr;
    aptr[q] = J.A + (size_t)(m0 + r) * J.Cin + seg;
    alds[q] = &As[(w * 32 + q * 16) * 32];
    bptr[q] = J.Wt + (size_t)(n0 + r) * J.Cin + seg;
    blds[q] = &Bs[(w * 32 + q * 16) * 32];
  }
  const int fr = l & 15, qd = l >> 4;
  const int wm = (w & 1) * 64, wn = (w >> 1) * 64;

  f32x4 acc[4][4];
#pragma unroll
  for (int i = 0; i < 4; ++i)
#pragma unroll
    for (int j = 0; j < 4; ++j)
#pragma unroll
      for (int r = 0; r < 4; ++r) acc[i][j][r] = 0.0f;

  const int kiters = J.Cin >> 5;
#pragma unroll 1
  for (int kk = 0; kk < kiters; ++kk) {
    __syncthreads();
    gl_lds16(aptr[0], alds[0]);
    gl_lds16(aptr[1], alds[1]);
    gl_lds16(bptr[0], blds[0]);
    gl_lds16(bptr[1], blds[1]);
    __syncthreads();
    aptr[0] += 32; aptr[1] += 32; bptr[0] += 32; bptr[1] += 32;
    bf16x8 af[4], bfv[4];
#pragma unroll
    for (int i = 0; i < 4; ++i)
      af[i] = *(const bf16x8*)&As[(wm + i * 16 + fr) * 32 + qd * 8];
#pragma unroll
    for (int j = 0; j < 4; ++j)
      bfv[j] = *(const bf16x8*)&Bs[(wn + j * 16 + fr) * 32 + qd * 8];
#pragma unroll
    for (int i = 0; i < 4; ++i)
#pragma unroll
      for (int j = 0; j < 4; ++j)
        acc[i][j] = __builtin_amdgcn_mfma_f32_16x16x32_bf16(af[i], bfv[j],
                                                            acc[i][j], 0, 0, 0);
  }

#pragma unroll
  for (int i = 0; i < 4; ++i) {
    const int mrow = m0 + wm + i * 16 + qd * 4;
#pragma unroll
    for (int j = 0; j < 4; ++j) {
      const int co = n0 + wn + j * 16 + fr;
      const float bv = J.bias[co];
#pragma unroll
      for (int r = 0; r < 4; ++r) {
        float v = acc[i][j][r] + bv;
        const int m = mrow + r;
        const int n = m >> J.lhw, hw = m & (HW - 1);
        const int y = hw >> J.lw, x = hw & (W - 1);
        J.outb[((size_t)n * J.onstride + (y + 1) * J.oWp + (x + 1)) * 256 + co] =
            (bf16_t)v;
      }
    }
  }
}

// ---------------- 3x3 conv with spatial A-reuse in LDS, Cin==256 -------------
// Proven 2-barrier structure (r3), LDS 44KB -> 3 blocks/CU.
// Normal path: 128Mx128N. Narrow path (pad_=1): 128Mx16N for Cout<=16 heads
// (reg tower): same A geometry (nAr/Pc as cls jobs), B = 3 taps x 16co x 32ci.
struct Job3 {
  const bf16_t* A;    // padded NHWC (halo zeros), pitch Wp, per-image nsA pixels
  const bf16_t* Wt;   // [9][256][256]
  const float* bias;
  bf16_t* outb;       // padded NHWC out (or null -> outf)
  const bf16_t* Wt2;  // second stream (ntiles==4): reg weights
  const float* bias2;
  bf16_t* outb2;
  int mtiles, ntiles, lw, lhw, Wp, nsA, oWp, onstride;
  int relu, Cout, pos_off, ch_off, use_outf, nAr, Pc, pad_;
};
struct Job3Pack { Job3 j[6]; };

__global__ __launch_bounds__(256, 3)
void conv3_batch(Job3Pack jp, float* __restrict__ outf) {
  __shared__ __align__(16) bf16_t As[320 * 32];   // spatial tile, 32 ch slice
  __shared__ __align__(16) bf16_t Bs[384 * 32];   // 3 taps x 128 co x 32 ci
  // XCD-aware chunked swizzle (grid % 8 == 0)
  const int cpx = gridDim.x >> 3;
  int b = (blockIdx.x & 7) * cpx + (blockIdx.x >> 3);
  int ji = 0;
#pragma unroll 1
  for (; ji < 5; ++ji) {
    int sz = jp.j[ji].mtiles * jp.j[ji].ntiles;
    if (b < sz) break;
    b -= sz;
  }
  const Job3 J = jp.j[ji];
  int s, mt;
  if (J.ntiles == 4)      { s = b & 3; mt = b >> 2; }
  else if (J.ntiles == 2) { s = b & 1; mt = b >> 1; }
  else                    { s = 0;     mt = b; }
  const int second = (s >= 2);
  const int n0 = (s & 1) * 128;
  const bf16_t* Wtp = second ? J.Wt2 : J.Wt;
  const float* biasp = second ? J.bias2 : J.bias;
  bf16_t* outbp = second ? J.outb2 : J.outb;
  const int t = threadIdx.x, l = t & 63, w = t >> 6;
  const int W = 1 << J.lw, HW = 1 << J.lhw;
  const int sr = l >> 2, seg = (l & 3) * 8;
  const int fr = l & 15, qd = l >> 4;

  const int m0 = mt * 128;
  const int n_img = m0 >> J.lhw;
  const int Y0 = (m0 & (HW - 1)) >> J.lw;
  const bf16_t* Ag = J.A + ((size_t)n_img * J.nsA + (size_t)Y0 * J.Wp) * 256;

  if (J.pad_) {
    // ---------- narrow path: M=128, N=16 (wave w -> rows w*32..w*32+31) ------
    int apix[2];
#pragma unroll
    for (int i = 0; i < 2; ++i) {
      const int m = w * 32 + i * 16 + fr;
      const int y = m >> J.lw, x = m & (W - 1);
      apix[i] = ((y + 1) * J.Wp + (x + 1)) * 32 + qd * 8;
    }
    f32x4 acc[2];
#pragma unroll
    for (int i = 0; i < 2; ++i)
#pragma unroll
      for (int r = 0; r < 4; ++r) acc[i][r] = 0.0f;

#pragma unroll 1
    for (int cb = 0; cb < 8; ++cb) {
      const int cboff = cb * 32;
#pragma unroll 1
      for (int ky = 0; ky < 3; ++ky) {
        __syncthreads();
        if (w < 3) {
          // tap (ky,w): 16 co x 32 ci = one gl_lds per wave
          gl_lds16(Wtp + (size_t)(ky * 3 + w) * 65536 +
                       (size_t)(l >> 2) * 256 + cboff + (l & 3) * 8,
                   &Bs[w * 512]);
        }
        if (ky == 0) {
#pragma unroll 1
          for (int r = 0; r < J.nAr; ++r) {
            int p = r * 64 + w * 16 + sr;
            p = (p < J.Pc) ? p : (J.Pc - 1);
            gl_lds16(Ag + (size_t)p * 256 + cboff + seg,
                     &As[(r * 64 + w * 16) * 32]);
          }
        }
        __syncthreads();
        const int dyoff = (ky - 1) * J.Wp * 32;
#pragma unroll
        for (int kx = 0; kx < 3; ++kx) {
          const int d = dyoff + (kx - 1) * 32;
          bf16x8 bfv = *(const bf16x8*)&Bs[kx * 512 + fr * 32 + qd * 8];
#pragma unroll
          for (int i = 0; i < 2; ++i) {
            bf16x8 af = *(const bf16x8*)&As[apix[i] + d];
            acc[i] = __builtin_amdgcn_mfma_f32_16x16x32_bf16(af, bfv,
                                                             acc[i], 0, 0, 0);
          }
        }
      }
    }
    const int co = fr;
    if (co < J.Cout) {
      const float bv = biasp[co];
#pragma unroll
      for (int i = 0; i < 2; ++i) {
        const int mrow = m0 + w * 32 + i * 16 + qd * 4;
#pragma unroll
        for (int r = 0; r < 4; ++r) {
          float v = acc[i][r] + bv;
          if (J.relu) v = fmaxf(v, 0.0f);
          const int m = mrow + r;
          const int n = m >> J.lhw, hw = m & (HW - 1);
          outf[((size_t)n * 5376 + J.pos_off + hw) * 252 + J.ch_off + co] = v;
        }
      }
    }
    return;
  }

  // ---------- normal path: M=128, N=128 (r3 proven body) ----------
  const int wm = (w & 1) * 64, wn = (w >> 1) * 64;

  // per-lane A-fragment base pixel offsets (tap (0,0) would be +(Wp+1)*32)
  int apix[4];
#pragma unroll
  for (int i = 0; i < 4; ++i) {
    const int m = wm + i * 16 + fr;
    const int y = m >> J.lw, x = m & (W - 1);
    apix[i] = ((y + 1) * J.Wp + (x + 1)) * 32 + qd * 8;
  }

  f32x4 acc[4][4];
#pragma unroll
  for (int i = 0; i < 4; ++i)
#pragma unroll
    for (int j = 0; j < 4; ++j)
#pragma unroll
      for (int r = 0; r < 4; ++r) acc[i][j][r] = 0.0f;

#pragma unroll 1
  for (int cb = 0; cb < 8; ++cb) {
    const int cboff = cb * 32;
#pragma unroll 1
    for (int ky = 0; ky < 3; ++ky) {
      __syncthreads();
      // stage B: taps (ky,0..2) -> 384 rows of 32ch, 6 rounds
#pragma unroll
      for (int r = 0; r < 6; ++r) {
        const int R = r * 64 + w * 16 + sr;
        const int tp = R >> 7, co = R & 127;
        gl_lds16(Wtp + (size_t)(ky * 3 + tp) * 65536 +
                     (size_t)(n0 + co) * 256 + cboff + seg,
                 &Bs[(r * 64 + w * 16) * 32]);
      }
      if (ky == 0) {
        // stage A: Pc contiguous padded pixels, 32-ch slice
#pragma unroll 1
        for (int r = 0; r < J.nAr; ++r) {
          int p = r * 64 + w * 16 + sr;
          p = (p < J.Pc) ? p : (J.Pc - 1);
          gl_lds16(Ag + (size_t)p * 256 + cboff + seg,
                   &As[(r * 64 + w * 16) * 32]);
        }
      }
      __syncthreads();
      const int dyoff = (ky - 1) * J.Wp * 32;
#pragma unroll
      for (int kx = 0; kx < 3; ++kx) {
        const int d = dyoff + (kx - 1) * 32;
        bf16x8 af[4], bfv[4];
#pragma unroll
        for (int i = 0; i < 4; ++i)
          af[i] = *(const bf16x8*)&As[apix[i] + d];
#pragma unroll
        for (int j = 0; j < 4; ++j)
          bfv[j] = *(const bf16x8*)&Bs[(kx * 128 + wn + j * 16 + fr) * 32 + qd * 8];
#pragma unroll
        for (int i = 0; i < 4; ++i)
#pragma unroll
          for (int j = 0; j < 4; ++j)
            acc[i][j] = __builtin_amdgcn_mfma_f32_16x16x32_bf16(af[i], bfv[j],
                                                                acc[i][j], 0, 0, 0);
      }
    }
  }

  // epilogue: D layout col=lane&15, row=(lane>>4)*4+reg
#pragma unroll
  for (int i = 0; i < 4; ++i) {
    const int mrow = m0 + wm + i * 16 + qd * 4;
#pragma unroll
    for (int j = 0; j < 4; ++j) {
      const int co = n0 + wn + j * 16 + fr;
      if (co < J.Cout) {
        const float bv = biasp[co];
#pragma unroll
        for (int r = 0; r < 4; ++r) {
          float v = acc[i][j][r] + bv;
          if (J.relu) v = fmaxf(v, 0.0f);
          const int m = mrow + r;
          const int n = m >> J.lhw, hw = m & (HW - 1);
          if (J.use_outf) {
            outf[((size_t)n * 5376 + J.pos_off + hw) * 252 + J.ch_off + co] = v;
          } else {
            const int y = hw >> J.lw, x = hw & (W - 1);
            outbp[((size_t)n * J.onstride + (y + 1) * J.oWp + (x + 1)) * 256 + co] =
                (bf16_t)v;
          }
        }
      }
    }
  }
}

// ---------------- launch -----------------------------------------------------
extern "C" void kernel_launch(void* const* d_in, const int* in_sizes, int n_in,
                              void* d_out, int out_size, void* d_ws, size_t ws_size,
                              hipStream_t stream) {
  const float* feat3 = (const float*)d_in[0];
  const float* feat4 = (const float*)d_in[1];
  const float* feat5 = (const float*)d_in[2];
  const float* lw0 = (const float*)d_in[3];  const float* lb0 = (const float*)d_in[4];
  const float* lw1 = (const float*)d_in[5];  const float* lb1 = (const float*)d_in[6];
  const float* lw2 = (const float*)d_in[7];  const float* lb2 = (const float*)d_in[8];
  const float* fw0 = (const float*)d_in[9];  const float* fb0 = (const float*)d_in[10];
  const float* fw1 = (const float*)d_in[11]; const float* fb1 = (const float*)d_in[12];
  const float* fw2 = (const float*)d_in[13]; const float* fb2 = (const float*)d_in[14];
  const float* cw0 = (const float*)d_in[15]; const float* cb0 = (const float*)d_in[16];
  const float* cw1 = (const float*)d_in[17]; const float* cb1 = (const float*)d_in[18];
  const float* cw2 = (const float*)d_in[19]; const float* cb2 = (const float*)d_in[20];
  const float* rw0 = (const float*)d_in[21]; const float* rb0 = (const float*)d_in[22];
  const float* rw1 = (const float*)d_in[23]; const float* rb1 = (const float*)d_in[24];
  const float* rw2 = (const float*)d_in[25]; const float* rb2 = (const float*)d_in[26];

  char* ws = (char*)d_ws;
  float* out = (float*)d_out;

  // ---- workspace layout (bytes) ----
  bf16_t* XS3 = (bf16_t*)(ws + 0);            // 33,554,432
  bf16_t* XS4 = (bf16_t*)(ws + 33554432);     // 16,777,216
  bf16_t* XS5 = (bf16_t*)(ws + 50331648);     //  8,388,608
  bf16_t* Lp0 = (bf16_t*)(ws + 58720256);     // 8*66*66*256*2 = 17,842,176
  bf16_t* Lp1 = (bf16_t*)(ws + 76562432);     // 8*34*34*256*2 =  4,734,976
  bf16_t* Lp2 = (bf16_t*)(ws + 81297408);     // 8*18*18*256*2 =  1,327,104
  bf16_t* Pp0 = (bf16_t*)(ws + 82624512);     // 17,842,176
  bf16_t* Pp1 = (bf16_t*)(ws + 100466688);    //  4,734,976
  bf16_t* Pp2 = (bf16_t*)(ws + 105201664);    //  1,327,104
  bf16_t* LWT0 = (bf16_t*)(ws + 106528768);   //    262,144
  bf16_t* LWT1 = (bf16_t*)(ws + 106790912);   //    524,288
  bf16_t* LWT2 = (bf16_t*)(ws + 107315200);   //  1,048,576
  bf16_t* W33  = (bf16_t*)(ws + 108363776);   // 9 * 1,179,648
  bf16_t* FWT0 = W33 + 0 * 589824;
  bf16_t* FWT1 = W33 + 1 * 589824;
  bf16_t* FWT2 = W33 + 2 * 589824;
  bf16_t* CWT0 = W33 + 3 * 589824;
  bf16_t* CWT1 = W33 + 4 * 589824;
  bf16_t* CWT2 = W33 + 5 * 589824;
  bf16_t* RWT0 = W33 + 6 * 589824;
  bf16_t* RWT1 = W33 + 7 * 589824;
  bf16_t* RWT2 = W33 + 8 * 589824;
  // T region: aliases XS3+XS4 (dead after laterals)
  bf16_t* TAc0 = (bf16_t*)(ws + 0);
  bf16_t* TAr0 = (bf16_t*)(ws + 17842176);
  bf16_t* TAc1 = (bf16_t*)(ws + 35684352);
  bf16_t* TAr1 = (bf16_t*)(ws + 40419328);
  bf16_t* TAc2 = (bf16_t*)(ws + 45154304);
  bf16_t* TAr2 = (bf16_t*)(ws + 46481408);    // end 47,808,512
  // Lp1n: fused-up2 output, reuses XS5 slot (dead after conv1)
  bf16_t* Lp1n = (bf16_t*)(ws + 50331648);    //  4,734,976 (fits in XS5's 8.4MB)
  bf16_t* TBc0 = Pp0; bf16_t* TBr0 = Lp0;
  bf16_t* TBc1 = Pp1; bf16_t* TBr1 = Lp1;
  bf16_t* TBc2 = Pp2; bf16_t* TBr2 = Lp2;

  // 1. mega-prep: weights + anchors + transposes + Lp/Pp rings (one launch)
  {
    PrepArgs P;
    P.s.lw0 = lw0; P.s.lw1 = lw1; P.s.lw2 = lw2;
    const float* w9s[9] = {fw0, fw1, fw2, cw0, cw1, cw2, rw0, rw1, rw2};
    int o9s[9] = {256, 256, 256, 256, 256, 240, 256, 256, 12};
    for (int i = 0; i < 9; ++i) { P.s.w9[i] = w9s[i]; P.s.O9[i] = o9s[i]; }
    P.feat3 = feat3; P.feat4 = feat4; P.feat5 = feat5;
    P.XS3 = XS3; P.XS4 = XS4; P.XS5 = XS5;
    P.LWT0 = LWT0; P.LWT1 = LWT1; P.LWT2 = LWT2; P.W33 = W33;
    P.anchors_out = out + 10838016;
    P.rz[0] = {Lp0, 66, 66, 4356, 260, 66560};
    P.rz[1] = {Lp1, 34, 34, 1156, 132, 33792};
    P.rz[2] = {Lp2, 18, 18, 324,  68,  17408};
    P.rz[3] = {Pp0, 66, 66, 4356, 260, 66560};
    P.rz[4] = {Pp1, 34, 34, 1156, 132, 33792};
    P.rz[5] = {Pp2, 18, 18, 324,  68,  17408};
    mega_prep<<<dim3(11351), 256, 0, stream>>>(P);
  }

  // 2. lateral 1x1 convs
  {
    Job1Pack jp;
    jp.j[0] = {XS3, LWT0, lb0, Lp0, 256, 6, 12, 66, 4356, 512, 0, 0};
    jp.j[1] = {XS4, LWT1, lb1, Lp1, 64, 5, 10, 34, 1156, 1024, 0, 0};
    jp.j[2] = {XS5, LWT2, lb2, Lp2, 16, 4, 8, 18, 324, 2048, 0, 0};
    conv1_batch<<<dim3(672), 256, 0, stream>>>(jp);
  }

  // 3. post-conv1: TA rings + Lp1n ring + fused top-down up2 (one launch)
  {
    Post1 P;
    P.rz[0] = {TAc0, 66, 66, 4356, 260, 66560};
    P.rz[1] = {TAr0, 66, 66, 4356, 260, 66560};
    P.rz[2] = {TAc1, 34, 34, 1156, 132, 33792};
    P.rz[3] = {TAr1, 34, 34, 1156, 132, 33792};
    P.rz[4] = {TAc2, 18, 18, 324,  68,  17408};
    P.rz[5] = {TAr2, 18, 18, 324,  68,  17408};
    P.rz[6] = {Lp1n, 34, 34, 1156, 132, 33792};
    P.Lp0 = Lp0; P.Lp1 = Lp1; P.Lp2 = Lp2; P.Lp1n = Lp1n;
    post1_k<<<dim3(6172), 256, 0, stream>>>(P);
  }

  auto mk3 = [](const bf16_t* A, const bf16_t* Wt, const float* bias,
                bf16_t* outb, int mtiles, int ntiles, int lw, int lhw,
                int Wp, int nsA, int oWp, int onstride, int relu, int Cout,
                int pos_off, int ch_off, int use_outf, int nAr, int Pc) {
    Job3 j;
    j.A = A; j.Wt = Wt; j.bias = bias; j.outb = outb;
    j.Wt2 = Wt; j.bias2 = bias; j.outb2 = outb;
    j.mtiles = mtiles; j.ntiles = ntiles; j.lw = lw; j.lhw = lhw;
    j.Wp = Wp; j.nsA = nsA; j.oWp = oWp; j.onstride = onstride;
    j.relu = relu; j.Cout = Cout; j.pos_off = pos_off; j.ch_off = ch_off;
    j.use_outf = use_outf; j.nAr = nAr; j.Pc = Pc; j.pad_ = 0;
    return j;
  };
  // level geometry: L0 (lw6,lhw12,Wp66,ns4356,mt256,nAr5,Pc264)
  //                 L1 (lw5,lhw10,Wp34,ns1156,mt64, nAr4,Pc204)
  //                 L2 (lw4,lhw8, Wp18,ns324, mt16, nAr3,Pc180)

  // 4. FPN 3x3 convs (672 blocks); L1 reads fused Lp1n
  {
    Job3Pack jp;
    jp.j[0] = mk3(Lp0, FWT0, fb0, Pp0, 256, 2, 6, 12, 66, 4356, 66, 4356, 0, 256, 0, 0, 0, 5, 264);
    jp.j[1] = mk3(Lp1n, FWT1, fb1, Pp1, 64, 2, 5, 10, 34, 1156, 34, 1156, 0, 256, 0, 0, 0, 4, 204);
    jp.j[2] = mk3(Lp2, FWT2, fb2, Pp2, 16, 2, 4, 8, 18, 324, 18, 324, 0, 256, 0, 0, 0, 3, 180);
    jp.j[3] = jp.j[4] = jp.j[5] = jp.j[2];
    jp.j[3].mtiles = jp.j[4].mtiles = jp.j[5].mtiles = 0;
    conv3_batch<<<dim3(672), 256, 0, stream>>>(jp, out);
  }

  // 5. tower stage 1 (1344 blocks): cls+reg paired per mt (nsub=4, shared A)
  {
    Job3Pack jp;
    jp.j[0] = mk3(Pp0, CWT0, cb0, TAc0, 256, 4, 6, 12, 66, 4356, 66, 4356, 1, 256, 0, 0, 0, 5, 264);
    jp.j[0].Wt2 = RWT0; jp.j[0].bias2 = rb0; jp.j[0].outb2 = TAr0;
    jp.j[1] = mk3(Pp1, CWT0, cb0, TAc1, 64, 4, 5, 10, 34, 1156, 34, 1156, 1, 256, 0, 0, 0, 4, 204);
    jp.j[1].Wt2 = RWT0; jp.j[1].bias2 = rb0; jp.j[1].outb2 = TAr1;
    jp.j[2] = mk3(Pp2, CWT0, cb0, TAc2, 16, 4, 4, 8, 18, 324, 18, 324, 1, 256, 0, 0, 0, 3, 180);
    jp.j[2].Wt2 = RWT0; jp.j[2].bias2 = rb0; jp.j[2].outb2 = TAr2;
    jp.j[3] = jp.j[4] = jp.j[5] = jp.j[2];
    jp.j[3].mtiles = jp.j[4].mtiles = jp.j[5].mtiles = 0;
    conv3_batch<<<dim3(1344), 256, 0, stream>>>(jp, out);
  }

  // 6. tower stage 2 (1344 blocks): inputs stream-disjoint, nsub=2
  {
    Job3Pack jp;
    jp.j[0] = mk3(TAc0, CWT1, cb1, TBc0, 256, 2, 6, 12, 66, 4356, 66, 4356, 1, 256, 0, 0, 0, 5, 264);
    jp.j[1] = mk3(TAr0, RWT1, rb1, TBr0, 256, 2, 6, 12, 66, 4356, 66, 4356, 1, 256, 0, 0, 0, 5, 264);
    jp.j[2] = mk3(TAc1, CWT1, cb1, TBc1, 64, 2, 5, 10, 34, 1156, 34, 1156, 1, 256, 0, 0, 0, 4, 204);
    jp.j[3] = mk3(TAr1, RWT1, rb1, TBr1, 64, 2, 5, 10, 34, 1156, 34, 1156, 1, 256, 0, 0, 0, 4, 204);
    jp.j[4] = mk3(TAc2, CWT1, cb1, TBc2, 16, 2, 4, 8, 18, 324, 18, 324, 1, 256, 0, 0, 0, 3, 180);
    jp.j[5] = mk3(TAr2, RWT1, rb1, TBr2, 16, 2, 4, 8, 18, 324, 18, 324, 1, 256, 0, 0, 0, 3, 180);
    conv3_batch<<<dim3(1344), 256, 0, stream>>>(jp, out);
  }

  // 7. tower stage 3 -> detector output (1008 blocks; reg heads narrow N=16)
  {
    Job3Pack jp;
    jp.j[0] = mk3(TBc0, CWT2, cb2, nullptr, 256, 2, 6, 12, 66, 4356, 0, 0, 0, 240, 0, 0, 1, 5, 264);
    jp.j[1] = mk3(TBr0, RWT2, rb2, nullptr, 256, 1, 6, 12, 66, 4356, 0, 0, 0, 12, 0, 240, 1, 5, 264);
    jp.j[1].pad_ = 1;
    jp.j[2] = mk3(TBc1, CWT2, cb2, nullptr, 64, 2, 5, 10, 34, 1156, 0, 0, 0, 240, 4096, 0, 1, 4, 204);
    jp.j[3] = mk3(TBr1, RWT2, rb2, nullptr, 64, 1, 5, 10, 34, 1156, 0, 0, 0, 12, 4096, 240, 1, 4, 204);
    jp.j[3].pad_ = 1;
    jp.j[4] = mk3(TBc2, CWT2, cb2, nullptr, 16, 2, 4, 8, 18, 324, 0, 0, 0, 240, 5120, 0, 1, 3, 180);
    jp.j[5] = mk3(TBr2, RWT2, rb2, nullptr, 16, 1, 4, 8, 18, 324, 0, 0, 0, 12, 5120, 240, 1, 3, 180);
    jp.j[5].pad_ = 1;
    conv3_batch<<<dim3(1008), 256, 0, stream>>>(jp, out);
  }
}

// Round 9
// 628.830 us; speedup vs baseline: 1.2674x; 1.2674x over previous
//
#include <hip/hip_runtime.h>

typedef __bf16 bf16_t;
typedef __bf16 bf16x4 __attribute__((ext_vector_type(4)));
typedef __bf16 bf16x8 __attribute__((ext_vector_type(8)));
typedef float f32x4 __attribute__((ext_vector_type(4)));

// async global->LDS, 16B per lane, wave-uniform LDS base + lane*16
__device__ inline void gl_lds16(const bf16_t* g, bf16_t* l) {
  __builtin_amdgcn_global_load_lds(
      (const __attribute__((address_space(1))) void*)g,
      (__attribute__((address_space(3))) void*)l, 16, 0, 0);
}

// ---------------- fp32 NCHW -> bf16 NHWC (LDS tile transpose) ----------------
// Write phase vectorized: each thread owns 8 consecutive channels of one pixel
// -> one bf16x8 (16B) store; 8 lanes = 128B contiguous, full 64B lines.
__global__ __launch_bounds__(256)
void nchw_to_nhwc(const float* __restrict__ in, bf16_t* __restrict__ out,
                  int C, int HW) {
  __shared__ float tile[64][65];
  const int n = blockIdx.z;
  const int c0 = blockIdx.y * 64, p0 = blockIdx.x * 64;
  const int t = threadIdx.x;
  const float* src = in + ((size_t)n * C + c0) * HW + p0;
  const int cl = t >> 6;
  const int pl = t & 63;
#pragma unroll
  for (int i = 0; i < 16; ++i)
    tile[cl + i * 4][pl] = src[(size_t)(cl + i * 4) * HW + pl];
  __syncthreads();
  bf16_t* dst = out + ((size_t)n * HW + p0) * C + c0;
  const int g = t & 7;        // channel-group (8 ch each)
  const int pbase = t >> 3;   // 32 pixels per pass
#pragma unroll
  for (int pass = 0; pass < 2; ++pass) {
    const int px = pbase + pass * 32;
    bf16x8 v;
#pragma unroll
    for (int j = 0; j < 8; ++j) v[j] = (bf16_t)tile[g * 8 + j][px];
    *(bf16x8*)&dst[(size_t)px * C + g * 8] = v;
  }
}

// ---------------- weight transforms, coalesced + anchors folded --------------
// blocks [0,896): LWT copy-cast, float4 read + bf16x4 write.
// blocks [896,3200): W33 transpose. One block per (sgi,o): thread ci reads the
//   9 CONSECUTIVE floats src[(o*256+ci)*9 + k], writes 9 kid-planes
//   (each a 128B-contiguous wave store).
// blocks [3200,3263): anchors.
struct WSrc {
  const float *lw0, *lw1, *lw2;
  const float* w9[9];   // fw0,fw1,fw2,cw0,cw1,cw2,rw0,rw1,rw2
  int O9[9];            // 256,256,256,256,256,240,256,256,12
};
__global__ __launch_bounds__(256)
void weight_prep(WSrc s, bf16_t* __restrict__ LWT0, bf16_t* __restrict__ LWT1,
                 bf16_t* __restrict__ LWT2, bf16_t* __restrict__ W33,
                 float* __restrict__ anchors_out) {
  const int bid = blockIdx.x;
  if (bid < 896) {
    const int idx = (bid * 256 + threadIdx.x) * 4;   // element index, %4==0
    const float* src;
    bf16_t* dst;
    int off;
    if (idx < 131072)      { src = s.lw0; dst = LWT0; off = idx; }
    else if (idx < 393216) { src = s.lw1; dst = LWT1; off = idx - 131072; }
    else                   { src = s.lw2; dst = LWT2; off = idx - 393216; }
    const f32x4 v = *(const f32x4*)&src[off];
    bf16x4 o4;
#pragma unroll
    for (int k = 0; k < 4; ++k) o4[k] = (bf16_t)v[k];
    *(bf16x4*)&dst[off] = o4;
    return;
  }
  if (bid < 3200) {
    const int r = bid - 896;           // sgi*256 + o
    const int sgi = r >> 8, o = r & 255;
    const int ci = threadIdx.x;
    const float* src = s.w9[sgi];
    const int O = s.O9[sgi];
    float v[9];
    if (o < O) {
      const float* p = &src[((size_t)o * 256 + ci) * 9];
#pragma unroll
      for (int k = 0; k < 9; ++k) v[k] = p[k];
    } else {
#pragma unroll
      for (int k = 0; k < 9; ++k) v[k] = 0.0f;
    }
    bf16_t* dst = W33 + (size_t)sgi * 589824 + o * 256 + ci;
#pragma unroll
    for (int k = 0; k < 9; ++k) dst[(size_t)k * 65536] = (bf16_t)v[k];
    return;
  }
  // anchors
  int rr = (bid - 3200) * 256 + threadIdx.x;
  if (rr >= 16128) return;
  int local, w, stride;
  float bs;
  if (rr < 12288)      { local = rr;          w = 64; stride = 8;  bs = 32.f;  }
  else if (rr < 15360) { local = rr - 12288;  w = 32; stride = 16; bs = 64.f;  }
  else                 { local = rr - 15360;  w = 16; stride = 32; bs = 128.f; }
  const int a = local % 3;
  const int sxy = local / 3;
  const int y = sxy / w, x = sxy - y * w;
  const float ar = (a == 0) ? 0.5f : (a == 1) ? 1.0f : 2.0f;
  const float sq = sqrtf(ar);
  const float hw_ = bs * sq * 0.5f, hh = bs / sq * 0.5f;
  const float cx = (float)x * (float)stride, cy = (float)y * (float)stride;
  anchors_out[(size_t)rr * 4 + 0] = cx - hw_;
  anchors_out[(size_t)rr * 4 + 1] = cy - hh;
  anchors_out[(size_t)rr * 4 + 2] = cx + hw_;
  anchors_out[(size_t)rr * 4 + 3] = cy + hh;
}

// ---------------- halo-ring zero helper --------------------------------------
struct BZJob { bf16_t* p; int Wp, Hp, nsA, ringN, count; };  // count = 8*ringN*32

__device__ inline void ring_zero_body(const BZJob& J, int idx) {
  if (idx >= J.count) return;
  const int c8 = idx & 31;
  const int rp = idx >> 5;
  const int n = rp / J.ringN;
  const int r = rp - n * J.ringN;
  int y, x;
  if (r < J.Wp)          { y = 0;         x = r; }
  else if (r < 2 * J.Wp) { y = J.Hp - 1;  x = r - J.Wp; }
  else {
    const int rr = r - 2 * J.Wp;
    y = 1 + (rr >> 1);
    x = (rr & 1) ? (J.Wp - 1) : 0;
  }
  bf16x8 z;
#pragma unroll
  for (int k = 0; k < 8; ++k) z[k] = (bf16_t)0.0f;
  *(bf16x8*)&J.p[((size_t)n * J.nsA + y * J.Wp + x) * 256 + c8 * 8] = z;
}

struct BZPack { BZJob j[6]; };
__global__ __launch_bounds__(256)
void zero_borders(BZPack bp) {
  int idx = blockIdx.x * 256 + threadIdx.x;
  int ji = 0;
#pragma unroll 1
  for (; ji < 5; ++ji) {
    if (idx < bp.j[ji].count) break;
    idx -= bp.j[ji].count;
  }
  ring_zero_body(bp.j[ji], idx);
}

// ---------------- post-conv1: TA rings + fused top-down up2 ------------------
// [0,1052): rings (6 TA jobs + Lp1n ring).
// [1052,2076): Lp1n = Lp1 + up2(Lp2)            (262144 elems of 8 ch)
// [2076,6172): Lp0 += up2(Lp1_old) + up4(Lp2)   (1048576 elems of 8 ch)
//   == Lp0 += up2(Lp1_new), since up2(Lp1n)[y,x] = Lp1[y>>1] + Lp2[y>>2].
struct Post1 {
  BZJob rz[7];
  bf16_t *Lp0, *Lp1, *Lp2, *Lp1n;
};
__global__ __launch_bounds__(256)
void post1_k(Post1 P) {
  const int bid = blockIdx.x;
  if (bid < 1052) {
    int idx = bid * 256 + threadIdx.x;
    int ji = 0;
#pragma unroll 1
    for (; ji < 6; ++ji) {
      if (idx < P.rz[ji].count) break;
      idx -= P.rz[ji].count;
    }
    ring_zero_body(P.rz[ji], idx);
    return;
  }
  if (bid < 2076) {
    const int idx = (bid - 1052) * 256 + threadIdx.x;   // < 262144
    const int c8 = idx & 31;
    const int pos = idx >> 5;
    const int n = pos >> 10;
    const int rem = pos & 1023;
    const int y = rem >> 5, x = rem & 31;
    const bf16_t* s1 = P.Lp1 + ((size_t)n * 1156 + (y + 1) * 34 + (x + 1)) * 256 + c8 * 8;
    const bf16_t* s2 = P.Lp2 + ((size_t)n * 324 + ((y >> 1) + 1) * 18 + ((x >> 1) + 1)) * 256 + c8 * 8;
    bf16_t* d = P.Lp1n + ((size_t)n * 1156 + (y + 1) * 34 + (x + 1)) * 256 + c8 * 8;
    bf16x8 a = *(const bf16x8*)s1;
    bf16x8 b = *(const bf16x8*)s2;
    bf16x8 o;
#pragma unroll
    for (int k = 0; k < 8; ++k) o[k] = (bf16_t)((float)a[k] + (float)b[k]);
    *(bf16x8*)d = o;
    return;
  }
  const int idx = (bid - 2076) * 256 + threadIdx.x;     // < 1048576
  const int c8 = idx & 31;
  const int pos = idx >> 5;
  const int n = pos >> 12;
  const int rem = pos & 4095;
  const int y = rem >> 6, x = rem & 63;
  bf16_t* d = P.Lp0 + ((size_t)n * 4356 + (y + 1) * 66 + (x + 1)) * 256 + c8 * 8;
  const bf16_t* s1 = P.Lp1 + ((size_t)n * 1156 + ((y >> 1) + 1) * 34 + ((x >> 1) + 1)) * 256 + c8 * 8;
  const bf16_t* s2 = P.Lp2 + ((size_t)n * 324 + ((y >> 2) + 1) * 18 + ((x >> 2) + 1)) * 256 + c8 * 8;
  bf16x8 dv = *(bf16x8*)d;
  bf16x8 a = *(const bf16x8*)s1;
  bf16x8 b = *(const bf16x8*)s2;
#pragma unroll
  for (int k = 0; k < 8; ++k)
    dv[k] = (bf16_t)((float)dv[k] + (float)a[k] + (float)b[k]);
  *(bf16x8*)d = dv;
}

// ---------------- 1x1 conv (laterals), bf16 MFMA (round-0 proven form) -------
struct Job1 {
  const bf16_t* A;    // unpadded NHWC
  const bf16_t* Wt;   // [256][Cin]
  const float* bias;
  bf16_t* outb;       // padded NHWC out
  int mtiles, lw, lhw, oWp, onstride, Cin, pad0, pad1;
};
struct Job1Pack { Job1 j[3]; };

__global__ __launch_bounds__(256, 2)
void conv1_batch(Job1Pack jp) {
  __shared__ __align__(16) bf16_t As[128 * 32];
  __shared__ __align__(16) bf16_t Bs[128 * 32];
  // XCD-aware chunked swizzle (grid % 8 == 0)
  const int cpx = gridDim.x >> 3;
  int b = (blockIdx.x & 7) * cpx + (blockIdx.x >> 3);
  int ji = 0;
#pragma unroll 1
  for (; ji < 2; ++ji) {
    int sz = jp.j[ji].mtiles * 2;
    if (b < sz) break;
    b -= sz;
  }
  const Job1 J = jp.j[ji];
  const int nt = b & 1, mt = b >> 1;
  const int m0 = mt * 128, n0 = nt * 128;
  const int t = threadIdx.x, l = t & 63, w = t >> 6;
  const int W = 1 << J.lw, HW = 1 << J.lhw;
  const int sr = l >> 2, seg = (l & 3) * 8;
  const bf16_t* aptr[2];
  const bf16_t* bptr[2];
  bf16_t* alds[2];
  bf16_t* blds[2];
#pragma unroll
  for (int q = 0; q < 2; ++q) {
    const int r = w * 32 + q * 16 + sr;
    aptr[q] = J.A + (size_t)(m0 + r) * J.Cin + seg;
    alds[q] = &As[(w * 32 + q * 16) * 32];
    bptr[q] = J.Wt + (size_t)(n0 + r) * J.Cin + seg;
    blds[q] = &Bs[(w * 32 + q * 16) * 32];
  }
  const int fr = l & 15, qd = l >> 4;
  const int wm = (w & 1) * 64, wn = (w >> 1) * 64;

  f32x4 acc[4][4];
#pragma unroll
  for (int i = 0; i < 4; ++i)
#pragma unroll
    for (int j = 0; j < 4; ++j)
#pragma unroll
      for (int r = 0; r < 4; ++r) acc[i][j][r] = 0.0f;

  const int kiters = J.Cin >> 5;
#pragma unroll 1
  for (int kk = 0; kk < kiters; ++kk) {
    __syncthreads();
    gl_lds16(aptr[0], alds[0]);
    gl_lds16(aptr[1], alds[1]);
    gl_lds16(bptr[0], blds[0]);
    gl_lds16(bptr[1], blds[1]);
    __syncthreads();
    aptr[0] += 32; aptr[1] += 32; bptr[0] += 32; bptr[1] += 32;
    bf16x8 af[4], bfv[4];
#pragma unroll
    for (int i = 0; i < 4; ++i)
      af[i] = *(const bf16x8*)&As[(wm + i * 16 + fr) * 32 + qd * 8];
#pragma unroll
    for (int j = 0; j < 4; ++j)
      bfv[j] = *(const bf16x8*)&Bs[(wn + j * 16 + fr) * 32 + qd * 8];
#pragma unroll
    for (int i = 0; i < 4; ++i)
#pragma unroll
      for (int j = 0; j < 4; ++j)
        acc[i][j] = __builtin_amdgcn_mfma_f32_16x16x32_bf16(af[i], bfv[j],
                                                            acc[i][j], 0, 0, 0);
  }

#pragma unroll
  for (int i = 0; i < 4; ++i) {
    const int mrow = m0 + wm + i * 16 + qd * 4;
#pragma unroll
    for (int j = 0; j < 4; ++j) {
      const int co = n0 + wn + j * 16 + fr;
      const float bv = J.bias[co];
#pragma unroll
      for (int r = 0; r < 4; ++r) {
        float v = acc[i][j][r] + bv;
        const int m = mrow + r;
        const int n = m >> J.lhw, hw = m & (HW - 1);
        const int y = hw >> J.lw, x = hw & (W - 1);
        J.outb[((size_t)n * J.onstride + (y + 1) * J.oWp + (x + 1)) * 256 + co] =
            (bf16_t)v;
      }
    }
  }
}

// ---------------- 3x3 conv with spatial A-reuse in LDS, Cin==256 -------------
// Proven 2-barrier structure (r3), LDS 44KB -> 3 blocks/CU.
// Normal path: 128Mx128N. Narrow path (pad_=1): 128Mx16N for Cout<=16 heads
// (reg tower): same A geometry (nAr/Pc as cls jobs), B = 3 taps x 16co x 32ci.
struct Job3 {
  const bf16_t* A;    // padded NHWC (halo zeros), pitch Wp, per-image nsA pixels
  const bf16_t* Wt;   // [9][256][256]
  const float* bias;
  bf16_t* outb;       // padded NHWC out (or null -> outf)
  const bf16_t* Wt2;  // second stream (ntiles==4): reg weights
  const float* bias2;
  bf16_t* outb2;
  int mtiles, ntiles, lw, lhw, Wp, nsA, oWp, onstride;
  int relu, Cout, pos_off, ch_off, use_outf, nAr, Pc, pad_;
};
struct Job3Pack { Job3 j[6]; };

__global__ __launch_bounds__(256, 3)
void conv3_batch(Job3Pack jp, float* __restrict__ outf) {
  __shared__ __align__(16) bf16_t As[320 * 32];   // spatial tile, 32 ch slice
  __shared__ __align__(16) bf16_t Bs[384 * 32];   // 3 taps x 128 co x 32 ci
  // XCD-aware chunked swizzle (grid % 8 == 0)
  const int cpx = gridDim.x >> 3;
  int b = (blockIdx.x & 7) * cpx + (blockIdx.x >> 3);
  int ji = 0;
#pragma unroll 1
  for (; ji < 5; ++ji) {
    int sz = jp.j[ji].mtiles * jp.j[ji].ntiles;
    if (b < sz) break;
    b -= sz;
  }
  const Job3 J = jp.j[ji];
  int s, mt;
  if (J.ntiles == 4)      { s = b & 3; mt = b >> 2; }
  else if (J.ntiles == 2) { s = b & 1; mt = b >> 1; }
  else                    { s = 0;     mt = b; }
  const int second = (s >= 2);
  const int n0 = (s & 1) * 128;
  const bf16_t* Wtp = second ? J.Wt2 : J.Wt;
  const float* biasp = second ? J.bias2 : J.bias;
  bf16_t* outbp = second ? J.outb2 : J.outb;
  const int t = threadIdx.x, l = t & 63, w = t >> 6;
  const int W = 1 << J.lw, HW = 1 << J.lhw;
  const int sr = l >> 2, seg = (l & 3) * 8;
  const int fr = l & 15, qd = l >> 4;

  const int m0 = mt * 128;
  const int n_img = m0 >> J.lhw;
  const int Y0 = (m0 & (HW - 1)) >> J.lw;
  const bf16_t* Ag = J.A + ((size_t)n_img * J.nsA + (size_t)Y0 * J.Wp) * 256;

  if (J.pad_) {
    // ---------- narrow path: M=128, N=16 (wave w -> rows w*32..w*32+31) ------
    int apix[2];
#pragma unroll
    for (int i = 0; i < 2; ++i) {
      const int m = w * 32 + i * 16 + fr;
      const int y = m >> J.lw, x = m & (W - 1);
      apix[i] = ((y + 1) * J.Wp + (x + 1)) * 32 + qd * 8;
    }
    f32x4 acc[2];
#pragma unroll
    for (int i = 0; i < 2; ++i)
#pragma unroll
      for (int r = 0; r < 4; ++r) acc[i][r] = 0.0f;

#pragma unroll 1
    for (int cb = 0; cb < 8; ++cb) {
      const int cboff = cb * 32;
#pragma unroll 1
      for (int ky = 0; ky < 3; ++ky) {
        __syncthreads();
        if (w < 3) {
          // tap (ky,w): 16 co x 32 ci = one gl_lds per wave
          gl_lds16(Wtp + (size_t)(ky * 3 + w) * 65536 +
                       (size_t)(l >> 2) * 256 + cboff + (l & 3) * 8,
                   &Bs[w * 512]);
        }
        if (ky == 0) {
#pragma unroll 1
          for (int r = 0; r < J.nAr; ++r) {
            int p = r * 64 + w * 16 + sr;
            p = (p < J.Pc) ? p : (J.Pc - 1);
            gl_lds16(Ag + (size_t)p * 256 + cboff + seg,
                     &As[(r * 64 + w * 16) * 32]);
          }
        }
        __syncthreads();
        const int dyoff = (ky - 1) * J.Wp * 32;
#pragma unroll
        for (int kx = 0; kx < 3; ++kx) {
          const int d = dyoff + (kx - 1) * 32;
          bf16x8 bfv = *(const bf16x8*)&Bs[kx * 512 + fr * 32 + qd * 8];
#pragma unroll
          for (int i = 0; i < 2; ++i) {
            bf16x8 af = *(const bf16x8*)&As[apix[i] + d];
            acc[i] = __builtin_amdgcn_mfma_f32_16x16x32_bf16(af, bfv,
                                                             acc[i], 0, 0, 0);
          }
        }
      }
    }
    const int co = fr;
    if (co < J.Cout) {
      const float bv = biasp[co];
#pragma unroll
      for (int i = 0; i < 2; ++i) {
        const int mrow = m0 + w * 32 + i * 16 + qd * 4;
#pragma unroll
        for (int r = 0; r < 4; ++r) {
          float v = acc[i][r] + bv;
          if (J.relu) v = fmaxf(v, 0.0f);
          const int m = mrow + r;
          const int n = m >> J.lhw, hw = m & (HW - 1);
          outf[((size_t)n * 5376 + J.pos_off + hw) * 252 + J.ch_off + co] = v;
        }
      }
    }
    return;
  }

  // ---------- normal path: M=128, N=128 (r3 proven body) ----------
  const int wm = (w & 1) * 64, wn = (w >> 1) * 64;

  // per-lane A-fragment base pixel offsets (tap (0,0) would be +(Wp+1)*32)
  int apix[4];
#pragma unroll
  for (int i = 0; i < 4; ++i) {
    const int m = wm + i * 16 + fr;
    const int y = m >> J.lw, x = m & (W - 1);
    apix[i] = ((y + 1) * J.Wp + (x + 1)) * 32 + qd * 8;
  }

  f32x4 acc[4][4];
#pragma unroll
  for (int i = 0; i < 4; ++i)
#pragma unroll
    for (int j = 0; j < 4; ++j)
#pragma unroll
      for (int r = 0; r < 4; ++r) acc[i][j][r] = 0.0f;

#pragma unroll 1
  for (int cb = 0; cb < 8; ++cb) {
    const int cboff = cb * 32;
#pragma unroll 1
    for (int ky = 0; ky < 3; ++ky) {
      __syncthreads();
      // stage B: taps (ky,0..2) -> 384 rows of 32ch, 6 rounds
#pragma unroll
      for (int r = 0; r < 6; ++r) {
        const int R = r * 64 + w * 16 + sr;
        const int tp = R >> 7, co = R & 127;
        gl_lds16(Wtp + (size_t)(ky * 3 + tp) * 65536 +
                     (size_t)(n0 + co) * 256 + cboff + seg,
                 &Bs[(r * 64 + w * 16) * 32]);
      }
      if (ky == 0) {
        // stage A: Pc contiguous padded pixels, 32-ch slice
#pragma unroll 1
        for (int r = 0; r < J.nAr; ++r) {
          int p = r * 64 + w * 16 + sr;
          p = (p < J.Pc) ? p : (J.Pc - 1);
          gl_lds16(Ag + (size_t)p * 256 + cboff + seg,
                   &As[(r * 64 + w * 16) * 32]);
        }
      }
      __syncthreads();
      const int dyoff = (ky - 1) * J.Wp * 32;
#pragma unroll
      for (int kx = 0; kx < 3; ++kx) {
        const int d = dyoff + (kx - 1) * 32;
        bf16x8 af[4], bfv[4];
#pragma unroll
        for (int i = 0; i < 4; ++i)
          af[i] = *(const bf16x8*)&As[apix[i] + d];
#pragma unroll
        for (int j = 0; j < 4; ++j)
          bfv[j] = *(const bf16x8*)&Bs[(kx * 128 + wn + j * 16 + fr) * 32 + qd * 8];
#pragma unroll
        for (int i = 0; i < 4; ++i)
#pragma unroll
          for (int j = 0; j < 4; ++j)
            acc[i][j] = __builtin_amdgcn_mfma_f32_16x16x32_bf16(af[i], bfv[j],
                                                                acc[i][j], 0, 0, 0);
      }
    }
  }

  // epilogue: D layout col=lane&15, row=(lane>>4)*4+reg
#pragma unroll
  for (int i = 0; i < 4; ++i) {
    const int mrow = m0 + wm + i * 16 + qd * 4;
#pragma unroll
    for (int j = 0; j < 4; ++j) {
      const int co = n0 + wn + j * 16 + fr;
      if (co < J.Cout) {
        const float bv = biasp[co];
#pragma unroll
        for (int r = 0; r < 4; ++r) {
          float v = acc[i][j][r] + bv;
          if (J.relu) v = fmaxf(v, 0.0f);
          const int m = mrow + r;
          const int n = m >> J.lhw, hw = m & (HW - 1);
          if (J.use_outf) {
            outf[((size_t)n * 5376 + J.pos_off + hw) * 252 + J.ch_off + co] = v;
          } else {
            const int y = hw >> J.lw, x = hw & (W - 1);
            outbp[((size_t)n * J.onstride + (y + 1) * J.oWp + (x + 1)) * 256 + co] =
                (bf16_t)v;
          }
        }
      }
    }
  }
}

// ---------------- launch -----------------------------------------------------
extern "C" void kernel_launch(void* const* d_in, const int* in_sizes, int n_in,
                              void* d_out, int out_size, void* d_ws, size_t ws_size,
                              hipStream_t stream) {
  const float* feat3 = (const float*)d_in[0];
  const float* feat4 = (const float*)d_in[1];
  const float* feat5 = (const float*)d_in[2];
  const float* lw0 = (const float*)d_in[3];  const float* lb0 = (const float*)d_in[4];
  const float* lw1 = (const float*)d_in[5];  const float* lb1 = (const float*)d_in[6];
  const float* lw2 = (const float*)d_in[7];  const float* lb2 = (const float*)d_in[8];
  const float* fw0 = (const float*)d_in[9];  const float* fb0 = (const float*)d_in[10];
  const float* fw1 = (const float*)d_in[11]; const float* fb1 = (const float*)d_in[12];
  const float* fw2 = (const float*)d_in[13]; const float* fb2 = (const float*)d_in[14];
  const float* cw0 = (const float*)d_in[15]; const float* cb0 = (const float*)d_in[16];
  const float* cw1 = (const float*)d_in[17]; const float* cb1 = (const float*)d_in[18];
  const float* cw2 = (const float*)d_in[19]; const float* cb2 = (const float*)d_in[20];
  const float* rw0 = (const float*)d_in[21]; const float* rb0 = (const float*)d_in[22];
  const float* rw1 = (const float*)d_in[23]; const float* rb1 = (const float*)d_in[24];
  const float* rw2 = (const float*)d_in[25]; const float* rb2 = (const float*)d_in[26];

  char* ws = (char*)d_ws;
  float* out = (float*)d_out;

  // ---- workspace layout (bytes) ----
  bf16_t* XS3 = (bf16_t*)(ws + 0);            // 33,554,432
  bf16_t* XS4 = (bf16_t*)(ws + 33554432);     // 16,777,216
  bf16_t* XS5 = (bf16_t*)(ws + 50331648);     //  8,388,608
  bf16_t* Lp0 = (bf16_t*)(ws + 58720256);     // 8*66*66*256*2 = 17,842,176
  bf16_t* Lp1 = (bf16_t*)(ws + 76562432);     // 8*34*34*256*2 =  4,734,976
  bf16_t* Lp2 = (bf16_t*)(ws + 81297408);     // 8*18*18*256*2 =  1,327,104
  bf16_t* Pp0 = (bf16_t*)(ws + 82624512);     // 17,842,176
  bf16_t* Pp1 = (bf16_t*)(ws + 100466688);    //  4,734,976
  bf16_t* Pp2 = (bf16_t*)(ws + 105201664);    //  1,327,104
  bf16_t* LWT0 = (bf16_t*)(ws + 106528768);   //    262,144
  bf16_t* LWT1 = (bf16_t*)(ws + 106790912);   //    524,288
  bf16_t* LWT2 = (bf16_t*)(ws + 107315200);   //  1,048,576
  bf16_t* W33  = (bf16_t*)(ws + 108363776);   // 9 * 1,179,648
  bf16_t* FWT0 = W33 + 0 * 589824;
  bf16_t* FWT1 = W33 + 1 * 589824;
  bf16_t* FWT2 = W33 + 2 * 589824;
  bf16_t* CWT0 = W33 + 3 * 589824;
  bf16_t* CWT1 = W33 + 4 * 589824;
  bf16_t* CWT2 = W33 + 5 * 589824;
  bf16_t* RWT0 = W33 + 6 * 589824;
  bf16_t* RWT1 = W33 + 7 * 589824;
  bf16_t* RWT2 = W33 + 8 * 589824;
  // T region: aliases XS3+XS4 (dead after laterals)
  bf16_t* TAc0 = (bf16_t*)(ws + 0);
  bf16_t* TAr0 = (bf16_t*)(ws + 17842176);
  bf16_t* TAc1 = (bf16_t*)(ws + 35684352);
  bf16_t* TAr1 = (bf16_t*)(ws + 40419328);
  bf16_t* TAc2 = (bf16_t*)(ws + 45154304);
  bf16_t* TAr2 = (bf16_t*)(ws + 46481408);    // end 47,808,512
  // Lp1n: fused-up2 output, reuses XS5 slot (dead after conv1)
  bf16_t* Lp1n = (bf16_t*)(ws + 50331648);    //  4,734,976 (fits in XS5's 8.4MB)
  bf16_t* TBc0 = Pp0; bf16_t* TBr0 = Lp0;
  bf16_t* TBc1 = Pp1; bf16_t* TBr1 = Lp1;
  bf16_t* TBc2 = Pp2; bf16_t* TBr2 = Lp2;

  // 1. weight prep (coalesced) + anchors folded in
  WSrc wsrc;
  wsrc.lw0 = lw0; wsrc.lw1 = lw1; wsrc.lw2 = lw2;
  const float* w9s[9] = {fw0, fw1, fw2, cw0, cw1, cw2, rw0, rw1, rw2};
  int o9s[9] = {256, 256, 256, 256, 256, 240, 256, 256, 12};
  for (int i = 0; i < 9; ++i) { wsrc.w9[i] = w9s[i]; wsrc.O9[i] = o9s[i]; }
  weight_prep<<<dim3(3263), 256, 0, stream>>>(wsrc, LWT0, LWT1, LWT2, W33,
                                              out + 10838016);

  // 2. activation casts to NHWC bf16
  nchw_to_nhwc<<<dim3(64, 8, 8),  256, 0, stream>>>(feat3, XS3, 512, 4096);
  nchw_to_nhwc<<<dim3(16, 16, 8), 256, 0, stream>>>(feat4, XS4, 1024, 1024);
  nchw_to_nhwc<<<dim3(4, 32, 8),  256, 0, stream>>>(feat5, XS5, 2048, 256);

  // 3. zero halo rings of Lp*/Pp* (interiors fully written by convs)
  {
    BZPack bp;
    bp.j[0] = {Lp0, 66, 66, 4356, 260, 66560};
    bp.j[1] = {Lp1, 34, 34, 1156, 132, 33792};
    bp.j[2] = {Lp2, 18, 18, 324,  68,  17408};
    bp.j[3] = {Pp0, 66, 66, 4356, 260, 66560};
    bp.j[4] = {Pp1, 34, 34, 1156, 132, 33792};
    bp.j[5] = {Pp2, 18, 18, 324,  68,  17408};
    zero_borders<<<dim3(920), 256, 0, stream>>>(bp);
  }

  // 4. lateral 1x1 convs
  {
    Job1Pack jp;
    jp.j[0] = {XS3, LWT0, lb0, Lp0, 256, 6, 12, 66, 4356, 512, 0, 0};
    jp.j[1] = {XS4, LWT1, lb1, Lp1, 64, 5, 10, 34, 1156, 1024, 0, 0};
    jp.j[2] = {XS5, LWT2, lb2, Lp2, 16, 4, 8, 18, 324, 2048, 0, 0};
    conv1_batch<<<dim3(672), 256, 0, stream>>>(jp);
  }

  // 5. post-conv1: TA rings + Lp1n ring + fused top-down up2 (one launch)
  {
    Post1 P;
    P.rz[0] = {TAc0, 66, 66, 4356, 260, 66560};
    P.rz[1] = {TAr0, 66, 66, 4356, 260, 66560};
    P.rz[2] = {TAc1, 34, 34, 1156, 132, 33792};
    P.rz[3] = {TAr1, 34, 34, 1156, 132, 33792};
    P.rz[4] = {TAc2, 18, 18, 324,  68,  17408};
    P.rz[5] = {TAr2, 18, 18, 324,  68,  17408};
    P.rz[6] = {Lp1n, 34, 34, 1156, 132, 33792};
    P.Lp0 = Lp0; P.Lp1 = Lp1; P.Lp2 = Lp2; P.Lp1n = Lp1n;
    post1_k<<<dim3(6172), 256, 0, stream>>>(P);
  }

  auto mk3 = [](const bf16_t* A, const bf16_t* Wt, const float* bias,
                bf16_t* outb, int mtiles, int ntiles, int lw, int lhw,
                int Wp, int nsA, int oWp, int onstride, int relu, int Cout,
                int pos_off, int ch_off, int use_outf, int nAr, int Pc) {
    Job3 j;
    j.A = A; j.Wt = Wt; j.bias = bias; j.outb = outb;
    j.Wt2 = Wt; j.bias2 = bias; j.outb2 = outb;
    j.mtiles = mtiles; j.ntiles = ntiles; j.lw = lw; j.lhw = lhw;
    j.Wp = Wp; j.nsA = nsA; j.oWp = oWp; j.onstride = onstride;
    j.relu = relu; j.Cout = Cout; j.pos_off = pos_off; j.ch_off = ch_off;
    j.use_outf = use_outf; j.nAr = nAr; j.Pc = Pc; j.pad_ = 0;
    return j;
  };
  // level geometry: L0 (lw6,lhw12,Wp66,ns4356,mt256,nAr5,Pc264)
  //                 L1 (lw5,lhw10,Wp34,ns1156,mt64, nAr4,Pc204)
  //                 L2 (lw4,lhw8, Wp18,ns324, mt16, nAr3,Pc180)

  // 6. FPN 3x3 convs (672 blocks); L1 reads fused Lp1n
  {
    Job3Pack jp;
    jp.j[0] = mk3(Lp0, FWT0, fb0, Pp0, 256, 2, 6, 12, 66, 4356, 66, 4356, 0, 256, 0, 0, 0, 5, 264);
    jp.j[1] = mk3(Lp1n, FWT1, fb1, Pp1, 64, 2, 5, 10, 34, 1156, 34, 1156, 0, 256, 0, 0, 0, 4, 204);
    jp.j[2] = mk3(Lp2, FWT2, fb2, Pp2, 16, 2, 4, 8, 18, 324, 18, 324, 0, 256, 0, 0, 0, 3, 180);
    jp.j[3] = jp.j[4] = jp.j[5] = jp.j[2];
    jp.j[3].mtiles = jp.j[4].mtiles = jp.j[5].mtiles = 0;
    conv3_batch<<<dim3(672), 256, 0, stream>>>(jp, out);
  }

  // 7. tower stage 1 (1344 blocks): cls+reg paired per mt (nsub=4, shared A)
  {
    Job3Pack jp;
    jp.j[0] = mk3(Pp0, CWT0, cb0, TAc0, 256, 4, 6, 12, 66, 4356, 66, 4356, 1, 256, 0, 0, 0, 5, 264);
    jp.j[0].Wt2 = RWT0; jp.j[0].bias2 = rb0; jp.j[0].outb2 = TAr0;
    jp.j[1] = mk3(Pp1, CWT0, cb0, TAc1, 64, 4, 5, 10, 34, 1156, 34, 1156, 1, 256, 0, 0, 0, 4, 204);
    jp.j[1].Wt2 = RWT0; jp.j[1].bias2 = rb0; jp.j[1].outb2 = TAr1;
    jp.j[2] = mk3(Pp2, CWT0, cb0, TAc2, 16, 4, 4, 8, 18, 324, 18, 324, 1, 256, 0, 0, 0, 3, 180);
    jp.j[2].Wt2 = RWT0; jp.j[2].bias2 = rb0; jp.j[2].outb2 = TAr2;
    jp.j[3] = jp.j[4] = jp.j[5] = jp.j[2];
    jp.j[3].mtiles = jp.j[4].mtiles = jp.j[5].mtiles = 0;
    conv3_batch<<<dim3(1344), 256, 0, stream>>>(jp, out);
  }

  // 8. tower stage 2 (1344 blocks): inputs stream-disjoint, nsub=2
  {
    Job3Pack jp;
    jp.j[0] = mk3(TAc0, CWT1, cb1, TBc0, 256, 2, 6, 12, 66, 4356, 66, 4356, 1, 256, 0, 0, 0, 5, 264);
    jp.j[1] = mk3(TAr0, RWT1, rb1, TBr0, 256, 2, 6, 12, 66, 4356, 66, 4356, 1, 256, 0, 0, 0, 5, 264);
    jp.j[2] = mk3(TAc1, CWT1, cb1, TBc1, 64, 2, 5, 10, 34, 1156, 34, 1156, 1, 256, 0, 0, 0, 4, 204);
    jp.j[3] = mk3(TAr1, RWT1, rb1, TBr1, 64, 2, 5, 10, 34, 1156, 34, 1156, 1, 256, 0, 0, 0, 4, 204);
    jp.j[4] = mk3(TAc2, CWT1, cb1, TBc2, 16, 2, 4, 8, 18, 324, 18, 324, 1, 256, 0, 0, 0, 3, 180);
    jp.j[5] = mk3(TAr2, RWT1, rb1, TBr2, 16, 2, 4, 8, 18, 324, 18, 324, 1, 256, 0, 0, 0, 3, 180);
    conv3_batch<<<dim3(1344), 256, 0, stream>>>(jp, out);
  }

  // 9. tower stage 3 -> detector output (1008 blocks; reg heads narrow N=16)
  {
    Job3Pack jp;
    jp.j[0] = mk3(TBc0, CWT2, cb2, nullptr, 256, 2, 6, 12, 66, 4356, 0, 0, 0, 240, 0, 0, 1, 5, 264);
    jp.j[1] = mk3(TBr0, RWT2, rb2, nullptr, 256, 1, 6, 12, 66, 4356, 0, 0, 0, 12, 0, 240, 1, 5, 264);
    jp.j[1].pad_ = 1;
    jp.j[2] = mk3(TBc1, CWT2, cb2, nullptr, 64, 2, 5, 10, 34, 1156, 0, 0, 0, 240, 4096, 0, 1, 4, 204);
    jp.j[3] = mk3(TBr1, RWT2, rb2, nullptr, 64, 1, 5, 10, 34, 1156, 0, 0, 0, 12, 4096, 240, 1, 4, 204);
    jp.j[3].pad_ = 1;
    jp.j[4] = mk3(TBc2, CWT2, cb2, nullptr, 16, 2, 4, 8, 18, 324, 0, 0, 0, 240, 5120, 0, 1, 3, 180);
    jp.j[5] = mk3(TBr2, RWT2, rb2, nullptr, 16, 1, 4, 8, 18, 324, 0, 0, 0, 12, 5120, 240, 1, 3, 180);
    jp.j[5].pad_ = 1;
    conv3_batch<<<dim3(1008), 256, 0, stream>>>(jp, out);
  }
}